// Round 4
// baseline (4882.750 us; speedup 1.0000x reference)
//
#include <hip/hip_runtime.h>
#include <stdint.h>

#define V 4096
#define D 128
#define E 12288
#define NPAD 16384
#define HALF 8192
#define TARGET 2048
#define MAXM (V - TARGET)    // 2048 max merges
#define ROWU32 256           // 4096 fields * 2 bits = 256 u32 per row (1 KB)
#define CAP 32               // candidates decided per round (exact machine)
#define LOGCAP 4096          // fixup log entries (16 KB LDS)

// s_waitcnt imms (gfx9): bits 3:0 vmcnt lo, 6:4 expcnt, 11:8 lgkmcnt, 15:14 vmcnt hi
#define WAIT_VM0   0x0F70    // vmcnt(0) only

// ws layout (bytes)
#define WS_N      0u                            // V*ROWU32*4 = 4 MB (2-bit matrix)
#define WS_PRI    (V * ROWU32 * 4u)             // V float
#define WS_KEYS   (WS_PRI + V * 4u)             // NPAD u64
#define WS_PK     (WS_KEYS + NPAD * 8u)         // E u32 (sorted packed edges)
#define WS_PAIRS  (WS_PK + E * 4u)              // MAXM u32
#define WS_MCOUNT (WS_PAIRS + MAXM * 4u)        // 1 int
#define WS_ALIVE  (WS_MCOUNT + 16u)             // V u8

typedef const __attribute__((address_space(1))) unsigned* gas1_t;
typedef __attribute__((address_space(3))) unsigned* las3_t;

__device__ __forceinline__ unsigned getf(const uint4& r, int c) {
    unsigned lo = (c & 2) ? r.z : r.x;
    unsigned hi = (c & 2) ? r.w : r.y;
    return (c & 1) ? hi : lo;
}
__device__ __forceinline__ void andf(uint4& r, int c, unsigned msk) {
    if (c == 0) r.x &= msk; else if (c == 1) r.y &= msk;
    else if (c == 2) r.z &= msk; else r.w &= msk;
}

__global__ void k_scatter(const int* __restrict__ edges, unsigned* __restrict__ n32) {
    int e = blockIdx.x * 256 + threadIdx.x;
    if (e < E) {
        int a = edges[e], b = edges[E + e];
        atomicOr(&n32[a * ROWU32 + (b >> 4)], 2u << ((b & 15) * 2));
        atomicOr(&n32[b * ROWU32 + (a >> 4)], 2u << ((a & 15) * 2));
    }
}

// numpy pairwise f32 sum for n=128 (matches np oracle reduction order)
__global__ void k_pri(const float* __restrict__ f, float* __restrict__ pri) {
    int v = blockIdx.x * 256 + threadIdx.x;
    if (v < V) {
        const float* p = f + v * D;
        float r[8];
#pragma unroll
        for (int j = 0; j < 8; j++) r[j] = __fmul_rn(p[j], p[j]);
        for (int i = 8; i < D; i += 8) {
#pragma unroll
            for (int j = 0; j < 8; j++)
                r[j] = __fadd_rn(r[j], __fmul_rn(p[i + j], p[i + j]));
        }
        float s01 = __fadd_rn(r[0], r[1]);
        float s23 = __fadd_rn(r[2], r[3]);
        float s45 = __fadd_rn(r[4], r[5]);
        float s67 = __fadd_rn(r[6], r[7]);
        pri[v] = __fadd_rn(__fadd_rn(s01, s23), __fadd_rn(s45, s67));
    }
}

__global__ void k_keys(const int* __restrict__ edges, const float* __restrict__ pri,
                       unsigned long long* __restrict__ keys) {
    int s = blockIdx.x * 256 + threadIdx.x;
    if (s < NPAD) {
        unsigned long long rec;
        if (s < E) {
            int a = edges[s], b = edges[E + s];
            float k = __fadd_rn(pri[a], pri[b]);   // epri >= 0 -> bits monotone
            rec = ((unsigned long long)__float_as_uint(k) << 32) | (unsigned)s;
        } else {
            rec = (0xFFFFFFFFull << 32) | (unsigned)s;
        }
        keys[s] = rec;
    }
}

// bitonic sort one 8192-element half in LDS; 2 blocks run concurrently
__launch_bounds__(1024)
__global__ void k_sort2(unsigned long long* __restrict__ keys) {
    __shared__ unsigned long long srt[HALF];
    const int tid = threadIdx.x;
    unsigned long long* base = keys + blockIdx.x * HALF;
    for (int s = tid; s < HALF; s += 1024) srt[s] = base[s];
    __syncthreads();
    for (int k = 2; k <= HALF; k <<= 1) {
        for (int j = k >> 1; j >= 1; j >>= 1) {
            for (int i = tid; i < HALF; i += 1024) {
                int ixj = i ^ j;
                if (ixj > i) {
                    unsigned long long x = srt[i], y = srt[ixj];
                    bool up = ((i & k) == 0);
                    if ((x > y) == up) { srt[i] = y; srt[ixj] = x; }
                }
            }
            __syncthreads();
        }
    }
    for (int s = tid; s < HALF; s += 1024) base[s] = srt[s];
}

// merge-path the two sorted halves; emit packed (v0<<16|v1) in global order
__launch_bounds__(64)
__global__ void k_mergepath(const unsigned long long* __restrict__ keys,
                            const int* __restrict__ edges, unsigned* __restrict__ pkG) {
    int t = blockIdx.x * 64 + threadIdx.x;
    if (t >= E / 64) return;
    const unsigned long long* A = keys;
    const unsigned long long* B = keys + HALF;
    int d = t * 64;
    int lo = d > HALF ? d - HALF : 0;
    int hi = d < HALF ? d : HALF;
    while (lo < hi) {
        int mid = (lo + hi) >> 1;
        if (A[mid] < B[d - 1 - mid]) lo = mid + 1; else hi = mid;
    }
    int ia = lo, ib = d - lo;
    for (int o = d; o < d + 64; o++) {
        bool takeA = (ib >= HALF) || (ia < HALF && A[ia] < B[ib]);
        unsigned long long r = takeA ? A[ia++] : B[ib++];
        int e = (int)(r & 0xFFFFFFFFull);
        int a = edges[e], b = edges[E + e];
        pkG[o] = ((unsigned)a << 16) | (unsigned)b;
    }
}

// ONE wave: candidate pool + EXACT in-round sequential oracle emulation.
// Per round: select top-32 undecided (priority order), fetch their rows into
// per-round LDS slots (deduped via last-writer-wins vertex->slot map), then
// sequentially process candidates exactly like the oracle: re-check each
// against CURRENT LDS state, apply kept merges in place (union row + fixups
// propagated to resident rows), so EVERY selected candidate is decided every
// round -- no conservative conflict blocking at all. Global matrix is made
// current at round end via kept-row write-back + fixup-log flush; the single
// vmcnt(0) drain at round top covers it.
__launch_bounds__(64, 1)
__global__ void k_collapse(const unsigned* __restrict__ pkG, unsigned* n32,
                           unsigned* __restrict__ pairsG, int* __restrict__ mcountG,
                           uint8_t* __restrict__ aliveG, float* __restrict__ out) {
    __shared__ unsigned shRows[64 * ROWU32];        // 64 KB: lane l owns slot l
    __shared__ uint8_t  alive[V];                   // 4 KB
    __shared__ uint8_t  shV2S[V];                   // 4 KB per-round vertex->slot
    __shared__ unsigned shCand[CAP];
    __shared__ unsigned shLog[LOGCAP];              // 16 KB: x<<16 | k<<2 | dx
    __shared__ int      shLogN;
    const int lane = threadIdx.x;
    for (int v = lane; v < V; v += 64) { alive[v] = 1; shV2S[v] = 0xFF; }
    __syncthreads();

    int cnt = V, mcount = 0, head = 64;
    unsigned pkv = pkG[lane];                       // pool: one candidate per lane
    bool dec = false;

    while (true) {
        const int a = (int)(pkv >> 16), b = (int)(pkv & 0xFFFFu);
        if (!dec && !(alive[a] && alive[b])) dec = true;
        // drain prior round's write-back/flush, then field check (3 absorbing)
        __builtin_amdgcn_s_waitcnt(WAIT_VM0);
        if (!dec) {
            unsigned wv = *(volatile unsigned*)(n32 + a * ROWU32 + (b >> 4));
            if (((wv >> ((b & 15) * 2)) & 3u) != 2u) dec = true;
        }
        unsigned long long mF = __ballot(!dec);

        int ev = -1;                                 // my slot-assign vertex
        if (mF) {
            int flagged = (int)__popcll(mF);
            int nacc = flagged < CAP ? flagged : CAP;
            int myK = -1;
            if (!dec) {
                int rank = (int)__popcll(mF & ((1ull << lane) - 1ull));
                if (rank < CAP) { myK = rank; shCand[rank] = pkv; }
            }
            if (lane == 0) shLogN = 0;
            __syncthreads();

            // ---- per-round slot map: endpoint -> lane slot (dup: one winner) ----
            if (lane < 2 * nacc) {
                unsigned cp = shCand[lane >> 1];
                ev = (lane & 1) ? (int)(cp & 0xFFFFu) : (int)(cp >> 16);
                shV2S[ev] = (uint8_t)lane;
            }
            __syncthreads();
            bool primary = (ev >= 0) && (shV2S[ev] == (uint8_t)lane);
            {
                unsigned long long mm = __ballot(primary);
                while (mm) {
                    int s = __ffsll((long long)mm) - 1; mm &= mm - 1ull;
                    int vv = __shfl(ev, s);
                    __builtin_amdgcn_global_load_lds(
                        (gas1_t)(n32 + vv * ROWU32 + lane * 4),
                        (las3_t)(shRows + s * ROWU32), 16, 0, 0);
                }
            }
            __builtin_amdgcn_s_waitcnt(WAIT_VM0);
            __syncthreads();

            // ---- EXACT sequential machine over shCand[0..nacc) ----
            const int limit = cnt - TARGET;          // > 0 here
            unsigned resid = (nacc >= 32) ? 0xFFFFFFFFu : ((1u << nacc) - 1u);
            unsigned keptM = 0u;
            int keptRound = 0;
            while (resid && keptRound < limit) {
                // parallel re-check of all residual candidates vs CURRENT state
                bool elig = false;
                if (lane < nacc && ((resid >> lane) & 1u)) {
                    unsigned cp = shCand[lane];
                    int v0 = (int)(cp >> 16), v1 = (int)(cp & 0xFFFFu);
                    if (alive[v0] && alive[v1]) {
                        int sA = shV2S[v0];
                        unsigned wv = shRows[sA * ROWU32 + (v1 >> 4)];
                        elig = ((wv >> ((v1 & 15) * 2)) & 3u) == 2u;
                    }
                }
                unsigned E32 = (unsigned)__ballot(elig);
                resid &= E32;                        // ineligible now = final reject
                if (!resid) break;
                const int k = __ffs(resid) - 1;      // lowest index = highest priority
                resid &= ~(1u << k);
                keptM |= 1u << k;
                const unsigned cp = shCand[k];
                const int v0 = (int)(cp >> 16), v1 = (int)(cp & 0xFFFFu);
                const int sA = shV2S[v0], sB = shV2S[v1];
                if (lane == 0) { alive[v1] = 0; pairsG[mcount] = cp; }
                mcount++; keptRound++;
                // phase A: reads (lane covers words 4*lane..4*lane+3)
                const uint4 ra = ((const uint4*)(shRows + sA * ROWU32))[lane];
                const uint4 rb = ((const uint4*)(shRows + sB * ROWU32))[lane];
                __syncthreads();
                // phase B: union row in place + fixups to resident rows + log
                uint4 rr;
                rr.x = ra.x | rb.x | ((ra.x & rb.x & 0xAAAAAAAAu) >> 1);
                rr.y = ra.y | rb.y | ((ra.y & rb.y & 0xAAAAAAAAu) >> 1);
                rr.z = ra.z | rb.z | ((ra.z & rb.z & 0xAAAAAAAAu) >> 1);
                rr.w = ra.w | rb.w | ((ra.w & rb.w & 0xAAAAAAAAu) >> 1);
                if ((v0 >> 6) == lane) andf(rr, (v0 >> 4) & 3, ~(3u << ((v0 & 15) * 2)));
                if ((v1 >> 6) == lane) andf(rr, (v1 >> 4) & 3, ~(3u << ((v1 & 15) * 2)));
                ((uint4*)(shRows + sA * ROWU32))[lane] = rr;
                const int wi0 = v0 >> 4, sh0 = (v0 & 15) * 2;
#pragma unroll
                for (int c = 0; c < 4; c++) {
                    unsigned bb = getf(rb, c);
                    if (!bb) continue;
                    unsigned aa = getf(ra, c);
                    int xbase = (lane << 6) + (c << 4);
                    unsigned tt = bb;
                    while (tt) {
                        int q = (__ffs(tt) - 1) >> 1;
                        tt &= ~(3u << (q * 2));
                        int x = xbase + q;
                        if (x != v0 && x != v1) {
                            unsigned a2 = (aa >> (q * 2)) & 3u;
                            unsigned b2 = (bb >> (q * 2)) & 3u;
                            unsigned n2 = a2 | b2 | ((a2 & b2 & 2u) >> 1);
                            unsigned dx = a2 ^ n2;
                            if (dx) {
                                int s = shV2S[x];    // unique x -> unique slot
                                if (s != 0xFF)
                                    shRows[s * ROWU32 + wi0] ^= (dx << sh0);
                                int li = atomicAdd(&shLogN, 1);
                                if (li < LOGCAP)
                                    shLog[li] = ((unsigned)x << 16) |
                                                ((unsigned)k << 2) | dx;
                            }
                        }
                    }
                }
                __syncthreads();
            }
            if (myK >= 0 && !((resid >> myK) & 1u)) dec = true;  // decided
            cnt -= keptRound;
            __syncthreads();

            // ---- write back kept rows + flush fixup log to global ----
            {
                unsigned km = keptM;
                while (km) {
                    int k2 = __ffs(km) - 1; km &= km - 1u;
                    int v0 = (int)(shCand[k2] >> 16);
                    int s = shV2S[v0];
                    ((uint4*)(n32 + v0 * ROWU32))[lane] =
                        ((const uint4*)(shRows + s * ROWU32))[lane];
                }
                int ln = shLogN; if (ln > LOGCAP) ln = LOGCAP;
                for (int e2 = lane; e2 < ln; e2 += 64) {
                    unsigned ent = shLog[e2];
                    int x = (int)(ent >> 16);
                    int k2 = (int)((ent >> 2) & 31u);
                    unsigned dx = ent & 3u;
                    bool skip = false;               // kept-v0 rows already written
                    unsigned km2 = keptM;
                    while (km2) {
                        int j = __ffs(km2) - 1; km2 &= km2 - 1u;
                        if ((int)(shCand[j] >> 16) == x) { skip = true; break; }
                    }
                    if (!skip) {
                        int v0 = (int)(shCand[k2] >> 16);
                        atomicXor(n32 + x * ROWU32 + (v0 >> 4),
                                  dx << ((v0 & 15) * 2));
                    }
                }
            }
            __syncthreads();
            if (ev >= 0) shV2S[ev] = 0xFF;           // clear per-round map
            if (cnt == TARGET) break;
        } else {
            if (head >= E) break;                    // pool empty, stream done
        }

        // ---- COMPACT undecided to low lanes (order-preserving) + REFILL ----
        {
            unsigned long long mU = __ballot(!dec);
            int nU = (int)__popcll(mU);
            int p = 0;
#pragma unroll
            for (int step = 32; step; step >>= 1) {
                int c2 = p + step;
                unsigned long long pref =
                    (c2 >= 64) ? ~0ull : ((1ull << c2) - 1ull);
                if ((int)__popcll(mU & pref) <= lane) p = c2;
            }
            unsigned npkv = (unsigned)__shfl((int)pkv, p);
            if (lane < nU) { pkv = npkv; dec = false; }
            else {
                int idx = head + lane - nU;
                if (idx < E) { pkv = pkG[idx]; dec = false; }
                else dec = true;                     // inactive forever
            }
            head += 64 - nU;
        }
    }

    for (int v = lane; v < V; v += 64) {
        uint8_t ao = alive[v];
        aliveG[v] = ao;
        out[V * D + v] = ao ? 1.0f : 0.0f;
    }
    if (lane == 0) { mcountG[0] = mcount; out[V * D + V] = (float)cnt; }
}

// Replay merge forest: per-vertex (root, weight) then scatter-add w*f[v] into out[root].
__launch_bounds__(256)
__global__ void k_apply(const float* __restrict__ f, const unsigned* __restrict__ pairsG,
                        const int* __restrict__ mcountG, float* __restrict__ out) {
    __shared__ unsigned pl[MAXM];
    __shared__ int rootL[256];
    __shared__ float wL[256];
    const int tid = threadIdx.x;
    const int mc = mcountG[0];
    for (int j = tid; j < mc; j += 256) pl[j] = pairsG[j];
    __syncthreads();
    int cur = blockIdx.x * 256 + tid;
    float w = 1.0f;
    for (int j = 0; j < mc; j++) {
        unsigned p = pl[j];
        int v0 = (int)(p >> 16), v1 = (int)(p & 0xFFFFu);
        if (cur == v1) { cur = v0; w *= 0.5f; }
        else if (cur == v0) w *= 0.5f;
    }
    rootL[tid] = cur;
    wL[tid] = w;
    __syncthreads();
    const int sub = tid >> 7;
    const int d = tid & 127;
    for (int s = 0; s < 256; s += 2) {
        int idx = s + sub;
        int vv = blockIdx.x * 256 + idx;
        atomicAdd(&out[rootL[idx] * D + d], wL[idx] * f[vv * D + d]);
    }
}

extern "C" void kernel_launch(void* const* d_in, const int* in_sizes, int n_in,
                              void* d_out, int out_size, void* d_ws, size_t ws_size,
                              hipStream_t stream) {
    (void)in_sizes; (void)n_in; (void)out_size; (void)ws_size;
    const float* features = (const float*)d_in[0];
    const int* edges = (const int*)d_in[1];
    uint8_t* ws = (uint8_t*)d_ws;
    unsigned* n32 = (unsigned*)(ws + WS_N);
    float* pri = (float*)(ws + WS_PRI);
    unsigned long long* keys = (unsigned long long*)(ws + WS_KEYS);
    unsigned* pkG = (unsigned*)(ws + WS_PK);
    unsigned* pairsG = (unsigned*)(ws + WS_PAIRS);
    int* mcountG = (int*)(ws + WS_MCOUNT);
    uint8_t* aliveG = ws + WS_ALIVE;
    float* out = (float*)d_out;

    hipMemsetAsync(n32, 0, (size_t)V * ROWU32 * 4, stream);
    hipMemsetAsync(out, 0, (size_t)V * D * sizeof(float), stream);
    k_pri<<<(V + 255) / 256, 256, 0, stream>>>(features, pri);
    k_scatter<<<(E + 255) / 256, 256, 0, stream>>>(edges, n32);
    k_keys<<<(NPAD + 255) / 256, 256, 0, stream>>>(edges, pri, keys);
    k_sort2<<<2, 1024, 0, stream>>>(keys);
    k_mergepath<<<(E / 64 + 63) / 64, 64, 0, stream>>>(keys, edges, pkG);
    k_collapse<<<1, 64, 0, stream>>>(pkG, n32, pairsG, mcountG, aliveG, out);
    k_apply<<<V / 256, 256, 0, stream>>>(features, pairsG, mcountG, out);
}